// Round 1
// baseline (72.394 us; speedup 1.0000x reference)
//
#include <hip/hip_runtime.h>

// Problem constants (from reference setup_inputs): B=8, L=4096, D=256, f32.
#define BATCH 8
#define SEQ   4096
#define DIM   256

// ---------------------------------------------------------------------------
// Kernel 1: per-(b, tile) affine aggregate.
// Block = 256 threads (one per d). Each thread sequentially composes the
// tile's operator (a_prod, x_agg) for its column:
//   state o elem_t : a' = a_t*a, x' = a_t*x + x_t   (complex)
// Coalesced: at each t, the 256 threads read 256 consecutive floats.
// ---------------------------------------------------------------------------
__global__ __launch_bounds__(DIM) void k_tile_agg(
    const float* __restrict__ Ar, const float* __restrict__ Ai,
    const float* __restrict__ Xr, const float* __restrict__ Xi,
    float4* __restrict__ agg, int NT, int T)
{
    int b = blockIdx.x / NT;
    int j = blockIdx.x - b * NT;
    int d = threadIdx.x;
    size_t base = ((size_t)b * SEQ + (size_t)j * T) * DIM + d;

    float ar = 1.f, ai = 0.f, xr = 0.f, xi = 0.f;
#pragma unroll 4
    for (int t = 0; t < T; ++t) {
        size_t idx = base + (size_t)t * DIM;
        float car = Ar[idx], cai = Ai[idx];
        float cxr = Xr[idx], cxi = Xi[idx];
        float nar = car * ar - cai * ai;
        float nai = car * ai + cai * ar;
        float nxr = car * xr - cai * xi + cxr;
        float nxi = car * xi + cai * xr + cxi;
        ar = nar; ai = nai; xr = nxr; xi = nxi;
    }
    agg[((size_t)b * NT + j) * DIM + d] = make_float4(ar, ai, xr, xi);
}

// ---------------------------------------------------------------------------
// Kernel 2: exclusive scan of tile aggregates along j for each (b,d).
// One thread per (b,d) = 2048 threads. Overwrites each slot with the
// incoming y (= x-part of the composite of tiles 0..j-1; y_init = 0).
// ---------------------------------------------------------------------------
__global__ __launch_bounds__(DIM) void k_scan_agg(float4* __restrict__ agg, int NT)
{
    int gid = blockIdx.x * blockDim.x + threadIdx.x;   // 0..B*DIM-1
    int b = gid / DIM;
    int d = gid - b * DIM;

    float ar = 1.f, ai = 0.f, xr = 0.f, xi = 0.f;      // composite of tiles < j
    for (int j = 0; j < NT; ++j) {
        size_t o = ((size_t)b * NT + j) * DIM + d;
        float4 v = agg[o];                             // tile j aggregate (a, x)
        agg[o] = make_float4(xr, xi, 0.f, 0.f);        // incoming y for tile j
        // composite' = tile_j o composite
        float nar = v.x * ar - v.y * ai;
        float nai = v.x * ai + v.y * ar;
        float nxr = v.x * xr - v.y * xi + v.z;
        float nxi = v.x * xi + v.y * xr + v.w;
        ar = nar; ai = nai; xr = nxr; xi = nxi;
    }
}

// ---------------------------------------------------------------------------
// Kernel 3: seed y from the tile prefix, recompute the recurrence, write out.
// Output layout [B,L,D,2] -> float2 per (b,t,d): 8 B/lane coalesced stores.
// Input re-read should hit L2/Infinity-Cache (written by kernel 1).
// ---------------------------------------------------------------------------
__global__ __launch_bounds__(DIM) void k_apply(
    const float* __restrict__ Ar, const float* __restrict__ Ai,
    const float* __restrict__ Xr, const float* __restrict__ Xi,
    const float4* __restrict__ agg, float2* __restrict__ out, int NT, int T)
{
    int b = blockIdx.x / NT;
    int j = blockIdx.x - b * NT;
    int d = threadIdx.x;

    float4 p = agg[((size_t)b * NT + j) * DIM + d];
    float yr = p.x, yi = p.y;

    size_t base = ((size_t)b * SEQ + (size_t)j * T) * DIM + d;
#pragma unroll 4
    for (int t = 0; t < T; ++t) {
        size_t idx = base + (size_t)t * DIM;
        float car = Ar[idx], cai = Ai[idx];
        float cxr = Xr[idx], cxi = Xi[idx];
        float nyr = car * yr - cai * yi + cxr;
        float nyi = car * yi + cai * yr + cxi;
        yr = nyr; yi = nyi;
        out[idx] = make_float2(yr, yi);
    }
}

extern "C" void kernel_launch(void* const* d_in, const int* in_sizes, int n_in,
                              void* d_out, int out_size, void* d_ws, size_t ws_size,
                              hipStream_t stream)
{
    const float* Ar = (const float*)d_in[0];
    const float* Ai = (const float*)d_in[1];
    const float* Xr = (const float*)d_in[2];
    const float* Xi = (const float*)d_in[3];
    float2* out = (float2*)d_out;
    float4* agg = (float4*)d_ws;

    // Pick the largest tile count whose aggregate buffer fits in d_ws.
    // bytes = BATCH * NT * DIM * sizeof(float4)
    int NT = 64;
    while (NT > 1 && (size_t)BATCH * NT * DIM * sizeof(float4) > ws_size) NT >>= 1;
    int T = SEQ / NT;

    dim3 block(DIM);
    dim3 grid1(BATCH * NT);
    k_tile_agg<<<grid1, block, 0, stream>>>(Ar, Ai, Xr, Xi, agg, NT, T);

    dim3 grid2((BATCH * DIM) / DIM);   // 8 blocks x 256 threads = 2048 threads
    k_scan_agg<<<grid2, block, 0, stream>>>(agg, NT);

    k_apply<<<grid1, block, 0, stream>>>(Ar, Ai, Xr, Xi, agg, out, NT, T);
}